// Round 3
// baseline (1789.954 us; speedup 1.0000x reference)
//
#include <hip/hip_runtime.h>
#include <cstdint>
#include <cstddef>

typedef _Float16 half8 __attribute__((ext_vector_type(8)));
typedef _Float16 half4v __attribute__((ext_vector_type(4)));
typedef float f32x4 __attribute__((ext_vector_type(4)));

#define NCOL 512   // 2*M interleaved (re,im)
#define KY 256     // 2*N interleaved

__device__ __forceinline__ float shrinkf(float v, float eta) {
  float a = fabsf(v) - eta;           // LAMBD = 1.0
  return a > 0.0f ? copysignf(a, v) : 0.0f;
}

// ---------- table builders ----------
// Wa[n=2p+c][k=2q+d], 512 x 256: realified A
__global__ void build_wa(const float* __restrict__ A, _Float16* __restrict__ Wa) {
  int idx = blockIdx.x * 256 + threadIdx.x;     // 131072
  int n = idx >> 8, k = idx & 255;
  int p = n >> 1, c = n & 1, q = k >> 1, d = k & 1;
  const float* A0 = A;                // (256,128)
  const float* A1 = A + 256 * 128;
  float v;
  if (c == 0) v = (d == 0) ? A0[p * 128 + q] : -A1[p * 128 + q];
  else        v = (d == 0) ? A1[p * 128 + q] :  A0[p * 128 + q];
  Wa[idx] = (_Float16)v;
}

// Wb = realify(B), 512 x 512 (single table, L2-resident forever)
__global__ void build_wb(const float* __restrict__ B, _Float16* __restrict__ Wb) {
  int idx = blockIdx.x * 256 + threadIdx.x;     // 262144
  int n = idx >> 9, k = idx & 511;
  int p = n >> 1, c = n & 1, q = k >> 1, d = k & 1;
  const float* B0 = B;                // (256,256)
  const float* B1 = B + 256 * 256;
  float v;
  if (c == 0) v = (d == 0) ?  B0[p * 256 + q] : -B1[p * 256 + q];
  else        v = (d == 0) ?  B1[p * 256 + q] :  B0[p * 256 + q];
  Wb[idx] = (_Float16)v;
}

// ---------- fused LISTA chain ----------
// Block = 64 batch rows, 4 waves; wave w owns features [w*128, w*128+128).
// Iteration: u = realify(B) @ x  (MFMA, W from L2), then
//   x_next = shrink(x_old + g*(Ay - u), eta)
// with x_old re-read from this thread's own LDS slot (b64) and Ay frags
// reloaded from ws (b64, 1-frag-ahead prefetch). No persistent Ay registers
// -> no spill (round-2 failure: 64-VGPR ayv spilled, +670 MB scratch reads).
__global__ __launch_bounds__(256, 2) void lista_fused(
    const float* __restrict__ y,
    const _Float16* __restrict__ Wa,
    const _Float16* __restrict__ Wb,
    _Float16* __restrict__ ayg,
    float* __restrict__ out,
    const float* __restrict__ gammas,
    const float* __restrict__ etas) {
  __shared__ __align__(16) _Float16 xlds[64 * 512];   // 64 KB

  const int tid  = threadIdx.x;
  const int l16  = tid & 15;
  const int quad = (tid >> 4) & 3;
  const int wave = tid >> 6;          // 0..3 feature slice
  const int l7   = l16 & 7;
  const int b0   = blockIdx.x << 6;   // batch base
  const int fb   = wave << 7;         // feature base
  const int fc   = fb >> 3;           // feature base in 8-half chunks

  f32x4 acc[8][4];
#pragma unroll
  for (int i = 0; i < 8; ++i)
#pragma unroll
    for (int j = 0; j < 4; ++j) acc[i][j] = {0.f, 0.f, 0.f, 0.f};

  // ---- prologue: acc = Ay tile = Wa(feat,K) @ y^T(K,batch), K=256 ----
#pragma unroll
  for (int kt = 0; kt < 4; ++kt) {
#pragma unroll
    for (int ks = 0; ks < 2; ++ks) {
      const int k0 = kt * 64 + ks * 32 + quad * 8;
      half8 bf[4];
#pragma unroll
      for (int j = 0; j < 4; ++j) {
        const float* yp = y + (size_t)(b0 + j * 16 + l16) * KY + k0;
        f32x4 a = *(const f32x4*)yp;
        f32x4 b = *(const f32x4*)(yp + 4);
        half8 h;
        h[0] = (_Float16)a.x; h[1] = (_Float16)a.y;
        h[2] = (_Float16)a.z; h[3] = (_Float16)a.w;
        h[4] = (_Float16)b.x; h[5] = (_Float16)b.y;
        h[6] = (_Float16)b.z; h[7] = (_Float16)b.w;
        bf[j] = h;
      }
#pragma unroll
      for (int ih = 0; ih < 2; ++ih) {
        half8 af[4];
#pragma unroll
        for (int i = 0; i < 4; ++i)
          af[i] = *(const half8*)(Wa + (size_t)(fb + (ih * 4 + i) * 16 + l16) * KY + k0);
#pragma unroll
        for (int i = 0; i < 4; ++i)
#pragma unroll
          for (int j = 0; j < 4; ++j)
            acc[ih * 4 + i][j] = __builtin_amdgcn_mfma_f32_16x16x32_f16(
                af[i], bf[j], acc[ih * 4 + i][j], 0, 0, 0);
      }
    }
  }

  // epilogue 0: spill Ay tile to ws (own frags), write x0 = shrink(g0*Ay) to LDS
  const float g0 = gammas[0], e0 = etas[0];
#pragma unroll
  for (int i = 0; i < 8; ++i) {
    const int cw = ((fc + i * 2 + (quad >> 1)) ^ l7) * 8 + (quad & 1) * 4;
#pragma unroll
    for (int j = 0; j < 4; ++j) {
      f32x4 v = acc[i][j];
      half4v a4 = {(_Float16)v.x, (_Float16)v.y, (_Float16)v.z, (_Float16)v.w};
      *(half4v*)(ayg + (size_t)(b0 + j * 16 + l16) * NCOL + fb + i * 16 + quad * 4) = a4;
      half4v x0 = {(_Float16)shrinkf(g0 * v.x, e0), (_Float16)shrinkf(g0 * v.y, e0),
                   (_Float16)shrinkf(g0 * v.z, e0), (_Float16)shrinkf(g0 * v.w, e0)};
      *(half4v*)(xlds + (j * 16 + l16) * NCOL + cw) = x0;
    }
  }

  // u = Wb @ x, fully unrolled K so the compiler can prefetch across steps
  auto run_gemm = [&]() {
#pragma unroll
    for (int i = 0; i < 8; ++i)
#pragma unroll
      for (int j = 0; j < 4; ++j) acc[i][j] = {0.f, 0.f, 0.f, 0.f};
#pragma unroll
    for (int kt = 0; kt < 8; ++kt) {
#pragma unroll
      for (int ks = 0; ks < 2; ++ks) {
        half8 bf[4];
#pragma unroll
        for (int j = 0; j < 4; ++j)
          bf[j] = *(const half8*)(xlds + (j * 16 + l16) * NCOL + kt * 64 +
                                  ((ks * 4 + quad) ^ l7) * 8);
        const size_t wk = (size_t)(kt * 64 + ks * 32 + quad * 8);
#pragma unroll
        for (int ih = 0; ih < 2; ++ih) {
          half8 af[4];
#pragma unroll
          for (int i = 0; i < 4; ++i)
            af[i] = *(const half8*)(Wb + (size_t)(fb + (ih * 4 + i) * 16 + l16) * NCOL + wk);
#pragma unroll
          for (int i = 0; i < 4; ++i)
#pragma unroll
            for (int j = 0; j < 4; ++j)
              acc[ih * 4 + i][j] = __builtin_amdgcn_mfma_f32_16x16x32_f16(
                  af[i], bf[j], acc[ih * 4 + i][j], 0, 0, 0);
        }
      }
    }
  };

  for (int t = 1; t <= 10; ++t) {
    __syncthreads();                  // x writes visible to all waves
    run_gemm();
    const float g = gammas[t], eta = etas[t];
    __syncthreads();                  // all reads of x done before overwrite

    half4v ayf[2][4];
#pragma unroll
    for (int j = 0; j < 4; ++j)
      ayf[0][j] = *(const half4v*)(ayg + (size_t)(b0 + j * 16 + l16) * NCOL + fb + quad * 4);

    if (t < 10) {
#pragma unroll
      for (int i = 0; i < 8; ++i) {
        if (i < 7) {
#pragma unroll
          for (int j = 0; j < 4; ++j)
            ayf[(i + 1) & 1][j] = *(const half4v*)(
                ayg + (size_t)(b0 + j * 16 + l16) * NCOL + fb + (i + 1) * 16 + quad * 4);
        }
        const int cw = ((fc + i * 2 + (quad >> 1)) ^ l7) * 8 + (quad & 1) * 4;
#pragma unroll
        for (int j = 0; j < 4; ++j) {
          half4v a4 = ayf[i & 1][j];
          half4v xo = *(const half4v*)(xlds + (j * 16 + l16) * NCOL + cw);
          f32x4 u = acc[i][j];
          half4v xn;
#pragma unroll
          for (int r = 0; r < 4; ++r) {
            float val = fmaf(g, (float)a4[r] - u[r], (float)xo[r]);
            xn[r] = (_Float16)shrinkf(val, eta);
          }
          *(half4v*)(xlds + (j * 16 + l16) * NCOL + cw) = xn;
        }
      }
    } else {
#pragma unroll
      for (int i = 0; i < 8; ++i) {
        if (i < 7) {
#pragma unroll
          for (int j = 0; j < 4; ++j)
            ayf[(i + 1) & 1][j] = *(const half4v*)(
                ayg + (size_t)(b0 + j * 16 + l16) * NCOL + fb + (i + 1) * 16 + quad * 4);
        }
        const int cw = ((fc + i * 2 + (quad >> 1)) ^ l7) * 8 + (quad & 1) * 4;
#pragma unroll
        for (int j = 0; j < 4; ++j) {
          half4v a4 = ayf[i & 1][j];
          half4v xo = *(const half4v*)(xlds + (j * 16 + l16) * NCOL + cw);
          f32x4 u = acc[i][j];
          f32x4 o;
#pragma unroll
          for (int r = 0; r < 4; ++r) {
            float val = fmaf(g, (float)a4[r] - u[r], (float)xo[r]);
            o[r] = shrinkf(val, eta);
          }
          *(f32x4*)(out + (size_t)(b0 + j * 16 + l16) * NCOL + fb + i * 16 + quad * 4) = o;
        }
      }
    }
  }
}

extern "C" void kernel_launch(void* const* d_in, const int* in_sizes, int n_in,
                              void* d_out, int out_size, void* d_ws, size_t ws_size,
                              hipStream_t stream) {
  const float* y      = (const float*)d_in[0];
  const float* A      = (const float*)d_in[1];
  const float* B      = (const float*)d_in[2];
  const float* etas   = (const float*)d_in[3];
  const float* gammas = (const float*)d_in[4];

  char* ws = (char*)d_ws;
  _Float16* Wa  = (_Float16*)ws;                      // 512*256*2 = 256 KB
  _Float16* Wb  = (_Float16*)(ws + 262144);           // 512*512*2 = 512 KB
  _Float16* ayg = (_Float16*)(ws + 786432);           // 65536*512*2 = 64 MB

  hipLaunchKernelGGL(build_wa, dim3(512), dim3(256), 0, stream, A, Wa);
  hipLaunchKernelGGL(build_wb, dim3(1024), dim3(256), 0, stream, B, Wb);
  hipLaunchKernelGGL(lista_fused, dim3(1024), dim3(256), 0, stream,
                     y, Wa, Wb, ayg, (float*)d_out, gammas, etas);
}

// Round 4
// 1102.073 us; speedup vs baseline: 1.6242x; 1.6242x over previous
//
#include <hip/hip_runtime.h>
#include <cstdint>
#include <cstddef>

typedef _Float16 half8 __attribute__((ext_vector_type(8)));
typedef _Float16 half4v __attribute__((ext_vector_type(4)));
typedef float f32x4 __attribute__((ext_vector_type(4)));

#define NCOL 512   // 2*M interleaved (re,im)
#define KY 256     // 2*N interleaved

__device__ __forceinline__ float shrinkf(float v, float eta) {
  float a = fabsf(v) - eta;           // LAMBD = 1.0
  return a > 0.0f ? copysignf(a, v) : 0.0f;
}

// ---------- table builders ----------
// Wa[n=2p+c][k=2q+d], 512 x 256: realified A
__global__ void build_wa(const float* __restrict__ A, _Float16* __restrict__ Wa) {
  int idx = blockIdx.x * 256 + threadIdx.x;     // 131072
  int n = idx >> 8, k = idx & 255;
  int p = n >> 1, c = n & 1, q = k >> 1, d = k & 1;
  const float* A0 = A;                // (256,128)
  const float* A1 = A + 256 * 128;
  float v;
  if (c == 0) v = (d == 0) ? A0[p * 128 + q] : -A1[p * 128 + q];
  else        v = (d == 0) ? A1[p * 128 + q] :  A0[p * 128 + q];
  Wa[idx] = (_Float16)v;
}

// Wb = realify(B), 512 x 512 (single table, L2-resident for all 10 iters)
__global__ void build_wb(const float* __restrict__ B, _Float16* __restrict__ Wb) {
  int idx = blockIdx.x * 256 + threadIdx.x;     // 262144
  int n = idx >> 9, k = idx & 511;
  int p = n >> 1, c = n & 1, q = k >> 1, d = k & 1;
  const float* B0 = B;                // (256,256)
  const float* B1 = B + 256 * 256;
  float v;
  if (c == 0) v = (d == 0) ?  B0[p * 256 + q] : -B1[p * 256 + q];
  else        v = (d == 0) ?  B1[p * 256 + q] :  B0[p * 256 + q];
  Wb[idx] = (_Float16)v;
}

// ---------- fused LISTA chain ----------
// Block = 64 batch rows, 4 waves; wave w owns features [w*128, w*128+128).
// Per t: u = realify(B) @ x (MFMA, Wb from L2), then
//   x_next = shrink(x_old + g*(Ay - u), eta)
// x in LDS (XOR-swizzled); Ay in ws, FRAGMENT-MAJOR layout:
//   ayg[(block*4+wave)*8192 + kk*256 + lane*4], kk = frag index (i*4+j)
//   -> every 8B-per-lane access is a 512B contiguous wave transaction.
// Register discipline (rounds 2/3 failed on spill):
//   t-loop unroll 1 (small code), kt unroll 2 (bounded pipelining),
//   ay via 2-deep named-register prefetch (static indexing only).
__global__ __launch_bounds__(256, 2) void lista_fused(
    const float* __restrict__ y,
    const _Float16* __restrict__ Wa,
    const _Float16* __restrict__ Wb,
    _Float16* __restrict__ ayg,
    float* __restrict__ out,
    const float* __restrict__ gammas,
    const float* __restrict__ etas) {
  __shared__ __align__(16) _Float16 xlds[64 * 512];   // 64 KB

  const int tid  = threadIdx.x;
  const int lane = tid & 63;
  const int l16  = tid & 15;
  const int quad = (tid >> 4) & 3;
  const int wave = tid >> 6;          // 0..3 feature slice
  const int l7   = l16 & 7;
  const int b0   = blockIdx.x << 6;   // batch base
  const int fb   = wave << 7;         // feature base
  const int fc   = fb >> 3;           // feature base in 8-half chunks
  const size_t ayb = ((size_t)blockIdx.x * 4 + wave) * 8192 + (size_t)lane * 4;

  f32x4 acc[8][4];
#pragma unroll
  for (int i = 0; i < 8; ++i)
#pragma unroll
    for (int j = 0; j < 4; ++j) acc[i][j] = {0.f, 0.f, 0.f, 0.f};

  // ---- prologue: acc = Ay tile = Wa(feat,K) @ y^T(K,batch), K=256 ----
#pragma unroll 1
  for (int kt = 0; kt < 4; ++kt) {
#pragma unroll
    for (int ks = 0; ks < 2; ++ks) {
      const int k0 = kt * 64 + ks * 32 + quad * 8;
      half8 bf[4];
#pragma unroll
      for (int j = 0; j < 4; ++j) {
        const float* yp = y + (size_t)(b0 + j * 16 + l16) * KY + k0;
        f32x4 a = *(const f32x4*)yp;
        f32x4 b = *(const f32x4*)(yp + 4);
        half8 h;
        h[0] = (_Float16)a.x; h[1] = (_Float16)a.y;
        h[2] = (_Float16)a.z; h[3] = (_Float16)a.w;
        h[4] = (_Float16)b.x; h[5] = (_Float16)b.y;
        h[6] = (_Float16)b.z; h[7] = (_Float16)b.w;
        bf[j] = h;
      }
#pragma unroll
      for (int ih = 0; ih < 2; ++ih) {
        half8 af[4];
#pragma unroll
        for (int i = 0; i < 4; ++i)
          af[i] = *(const half8*)(Wa + (size_t)(fb + (ih * 4 + i) * 16 + l16) * KY + k0);
#pragma unroll
        for (int i = 0; i < 4; ++i)
#pragma unroll
          for (int j = 0; j < 4; ++j)
            acc[ih * 4 + i][j] = __builtin_amdgcn_mfma_f32_16x16x32_f16(
                af[i], bf[j], acc[ih * 4 + i][j], 0, 0, 0);
      }
    }
  }

  // epilogue 0: Ay -> ws (fragment-major, coalesced); x0 = shrink(g0*Ay) -> LDS
  const float g0 = gammas[0], e0 = etas[0];
#pragma unroll
  for (int i = 0; i < 8; ++i) {
    const int cw = ((fc + i * 2 + (quad >> 1)) ^ l7) * 8 + (quad & 1) * 4;
#pragma unroll
    for (int j = 0; j < 4; ++j) {
      f32x4 v = acc[i][j];
      half4v a4 = {(_Float16)v.x, (_Float16)v.y, (_Float16)v.z, (_Float16)v.w};
      *(half4v*)(ayg + ayb + (size_t)(i * 4 + j) * 256) = a4;
      half4v x0 = {(_Float16)shrinkf(g0 * v.x, e0), (_Float16)shrinkf(g0 * v.y, e0),
                   (_Float16)shrinkf(g0 * v.z, e0), (_Float16)shrinkf(g0 * v.w, e0)};
      *(half4v*)(xlds + (j * 16 + l16) * NCOL + cw) = x0;
    }
  }

  // ---- main loop: x = shrink(x + g*(Ay - Wb@x)), t = 1..10 ----
#pragma unroll 1
  for (int t = 1; t <= 10; ++t) {
    __syncthreads();                  // x writes visible to all waves

#pragma unroll
    for (int i = 0; i < 8; ++i)
#pragma unroll
      for (int j = 0; j < 4; ++j) acc[i][j] = {0.f, 0.f, 0.f, 0.f};

#pragma unroll 2
    for (int kt = 0; kt < 8; ++kt) {
#pragma unroll
      for (int ks = 0; ks < 2; ++ks) {
        half8 bf[4];
#pragma unroll
        for (int j = 0; j < 4; ++j)
          bf[j] = *(const half8*)(xlds + (j * 16 + l16) * NCOL + kt * 64 +
                                  ((ks * 4 + quad) ^ l7) * 8);
        const size_t wk = (size_t)(kt * 64 + ks * 32 + quad * 8);
#pragma unroll
        for (int ih = 0; ih < 2; ++ih) {
          half8 af[4];
#pragma unroll
          for (int i = 0; i < 4; ++i)
            af[i] = *(const half8*)(Wb + (size_t)(fb + (ih * 4 + i) * 16 + l16) * NCOL + wk);
#pragma unroll
          for (int i = 0; i < 4; ++i)
#pragma unroll
            for (int j = 0; j < 4; ++j)
              acc[ih * 4 + i][j] = __builtin_amdgcn_mfma_f32_16x16x32_f16(
                  af[i], bf[j], acc[ih * 4 + i][j], 0, 0, 0);
        }
      }
    }

    const float g = gammas[t], eta = etas[t];
    __syncthreads();                  // all reads of x done before overwrite

    // 2-deep Ay prefetch, all statically indexed
    half4v ap0 = *(const half4v*)(ayg + ayb);
    half4v ap1 = *(const half4v*)(ayg + ayb + 256);
    if (t < 10) {
#pragma unroll
      for (int i = 0; i < 8; ++i) {
        const int cw = ((fc + i * 2 + (quad >> 1)) ^ l7) * 8 + (quad & 1) * 4;
#pragma unroll
        for (int j = 0; j < 4; ++j) {
          const int kk = i * 4 + j;
          half4v a4 = ap0;
          ap0 = ap1;
          if (kk + 2 < 32) ap1 = *(const half4v*)(ayg + ayb + (size_t)(kk + 2) * 256);
          half4v xo = *(const half4v*)(xlds + (j * 16 + l16) * NCOL + cw);
          f32x4 u = acc[i][j];
          half4v xn;
#pragma unroll
          for (int r = 0; r < 4; ++r) {
            float val = fmaf(g, (float)a4[r] - u[r], (float)xo[r]);
            xn[r] = (_Float16)shrinkf(val, eta);
          }
          *(half4v*)(xlds + (j * 16 + l16) * NCOL + cw) = xn;
        }
      }
    } else {
#pragma unroll
      for (int i = 0; i < 8; ++i) {
        const int cw = ((fc + i * 2 + (quad >> 1)) ^ l7) * 8 + (quad & 1) * 4;
#pragma unroll
        for (int j = 0; j < 4; ++j) {
          const int kk = i * 4 + j;
          half4v a4 = ap0;
          ap0 = ap1;
          if (kk + 2 < 32) ap1 = *(const half4v*)(ayg + ayb + (size_t)(kk + 2) * 256);
          half4v xo = *(const half4v*)(xlds + (j * 16 + l16) * NCOL + cw);
          f32x4 u = acc[i][j];
          f32x4 o;
#pragma unroll
          for (int r = 0; r < 4; ++r) {
            float val = fmaf(g, (float)a4[r] - u[r], (float)xo[r]);
            o[r] = shrinkf(val, eta);
          }
          *(f32x4*)(out + (size_t)(b0 + j * 16 + l16) * NCOL + fb + i * 16 + quad * 4) = o;
        }
      }
    }
  }
}

extern "C" void kernel_launch(void* const* d_in, const int* in_sizes, int n_in,
                              void* d_out, int out_size, void* d_ws, size_t ws_size,
                              hipStream_t stream) {
  const float* y      = (const float*)d_in[0];
  const float* A      = (const float*)d_in[1];
  const float* B      = (const float*)d_in[2];
  const float* etas   = (const float*)d_in[3];
  const float* gammas = (const float*)d_in[4];

  char* ws = (char*)d_ws;
  _Float16* Wa  = (_Float16*)ws;                      // 512*256*2 = 256 KB
  _Float16* Wb  = (_Float16*)(ws + 262144);           // 512*512*2 = 512 KB
  _Float16* ayg = (_Float16*)(ws + 786432);           // 65536*512*2 = 64 MB

  hipLaunchKernelGGL(build_wa, dim3(512), dim3(256), 0, stream, A, Wa);
  hipLaunchKernelGGL(build_wb, dim3(1024), dim3(256), 0, stream, B, Wb);
  hipLaunchKernelGGL(lista_fused, dim3(1024), dim3(256), 0, stream,
                     y, Wa, Wb, ayg, (float*)d_out, gammas, etas);
}

// Round 5
// 919.574 us; speedup vs baseline: 1.9465x; 1.1985x over previous
//
#include <hip/hip_runtime.h>
#include <cstdint>
#include <cstddef>

typedef _Float16 half8 __attribute__((ext_vector_type(8)));
typedef _Float16 half4v __attribute__((ext_vector_type(4)));
typedef float f32x4 __attribute__((ext_vector_type(4)));

#define NCOL 512   // 2*M interleaved (re,im)
#define KY 256     // 2*N interleaved

__device__ __forceinline__ float shrinkf(float v, float eta) {
  float a = fabsf(v) - eta;           // LAMBD = 1.0
  return a > 0.0f ? copysignf(a, v) : 0.0f;
}

// ---------- table builders ----------
// Wa[n=2p+c][k=2q+d], 512 x 256: realified A
__global__ void build_wa(const float* __restrict__ A, _Float16* __restrict__ Wa) {
  int idx = blockIdx.x * 256 + threadIdx.x;     // 131072
  int n = idx >> 8, k = idx & 255;
  int p = n >> 1, c = n & 1, q = k >> 1, d = k & 1;
  const float* A0 = A;                // (256,128)
  const float* A1 = A + 256 * 128;
  float v;
  if (c == 0) v = (d == 0) ? A0[p * 128 + q] : -A1[p * 128 + q];
  else        v = (d == 0) ? A1[p * 128 + q] :  A0[p * 128 + q];
  Wa[idx] = (_Float16)v;
}

// Wb = realify(B), 512 x 512 (single table, L2-resident for all 10 iters)
__global__ void build_wb(const float* __restrict__ B, _Float16* __restrict__ Wb) {
  int idx = blockIdx.x * 256 + threadIdx.x;     // 262144
  int n = idx >> 9, k = idx & 511;
  int p = n >> 1, c = n & 1, q = k >> 1, d = k & 1;
  const float* B0 = B;                // (256,256)
  const float* B1 = B + 256 * 256;
  float v;
  if (c == 0) v = (d == 0) ?  B0[p * 256 + q] : -B1[p * 256 + q];
  else        v = (d == 0) ?  B1[p * 256 + q] :  B0[p * 256 + q];
  Wb[idx] = (_Float16)v;
}

// ---------- fused LISTA chain ----------
// Block = 64 batch rows, 512 threads / 8 waves; wave w owns features
// [w*64, w*64+64). Per t: u = realify(B) @ x (MFMA, Wb from L2), then
//   x_next = shrink(x_old + g*(Ay - u), eta)
// x in LDS [64][512] fp16, 16B-chunk XOR swizzle (chunk ^= batch&7).
// Ay in REGISTERS: per-wave tile is only 64x64 -> acc 64 AGPR + ayv 32 VGPR,
// fits the 256-reg budget at 2 waves/SIMD (rounds 2-4 failure mode was
// ay spill / ay HBM round-trips; both eliminated here).
__global__ __launch_bounds__(512, 2) void lista_fused(
    const float* __restrict__ y,
    const _Float16* __restrict__ Wa,
    const _Float16* __restrict__ Wb,
    float* __restrict__ out,
    const float* __restrict__ gammas,
    const float* __restrict__ etas) {
  __shared__ __align__(16) _Float16 xlds[64 * 512];   // 64 KB

  const int tid  = threadIdx.x;
  const int l16  = tid & 15;
  const int quad = (tid >> 4) & 3;
  const int wave = tid >> 6;          // 0..7 feature slice
  const int l7   = l16 & 7;
  const int b0   = blockIdx.x << 6;   // batch base
  const int fb   = wave << 6;         // feature base (64 per wave)
  const int fc   = wave << 3;         // feature base in 8-half chunks

  f32x4 acc[4][4];
#pragma unroll
  for (int i = 0; i < 4; ++i)
#pragma unroll
    for (int j = 0; j < 4; ++j) acc[i][j] = {0.f, 0.f, 0.f, 0.f};

  // ---- prologue: acc = Ay tile = Wa(feat,K) @ y^T(K,batch), K=256 ----
#pragma unroll 1
  for (int kt = 0; kt < 4; ++kt) {
#pragma unroll
    for (int ks = 0; ks < 2; ++ks) {
      const int k0 = kt * 64 + ks * 32 + quad * 8;
      half8 bf[4];
#pragma unroll
      for (int j = 0; j < 4; ++j) {
        const float* yp = y + (size_t)(b0 + j * 16 + l16) * KY + k0;
        f32x4 a = *(const f32x4*)yp;
        f32x4 b = *(const f32x4*)(yp + 4);
        half8 h;
        h[0] = (_Float16)a.x; h[1] = (_Float16)a.y;
        h[2] = (_Float16)a.z; h[3] = (_Float16)a.w;
        h[4] = (_Float16)b.x; h[5] = (_Float16)b.y;
        h[6] = (_Float16)b.z; h[7] = (_Float16)b.w;
        bf[j] = h;
      }
      half8 af[4];
#pragma unroll
      for (int i = 0; i < 4; ++i)
        af[i] = *(const half8*)(Wa + (size_t)(fb + i * 16 + l16) * KY + k0);
#pragma unroll
      for (int i = 0; i < 4; ++i)
#pragma unroll
        for (int j = 0; j < 4; ++j)
          acc[i][j] = __builtin_amdgcn_mfma_f32_16x16x32_f16(
              af[i], bf[j], acc[i][j], 0, 0, 0);
    }
  }

  // epilogue 0: Ay -> registers (fp16 packed); x0 = shrink(g0*Ay) -> LDS
  const float g0 = gammas[0], e0 = etas[0];
  half4v ayv[4][4];
#pragma unroll
  for (int i = 0; i < 4; ++i) {
    const int cw = ((fc + i * 2 + (quad >> 1)) ^ l7) * 8 + (quad & 1) * 4;
#pragma unroll
    for (int j = 0; j < 4; ++j) {
      f32x4 v = acc[i][j];
      half4v a4 = {(_Float16)v.x, (_Float16)v.y, (_Float16)v.z, (_Float16)v.w};
      ayv[i][j] = a4;
      half4v x0 = {(_Float16)shrinkf(g0 * v.x, e0), (_Float16)shrinkf(g0 * v.y, e0),
                   (_Float16)shrinkf(g0 * v.z, e0), (_Float16)shrinkf(g0 * v.w, e0)};
      *(half4v*)(xlds + (j * 16 + l16) * NCOL + cw) = x0;
    }
  }

  // ---- main loop: x = shrink(x + g*(Ay - Wb@x)), t = 1..10 ----
#pragma unroll 1
  for (int t = 1; t <= 10; ++t) {
    __syncthreads();                  // x writes visible to all waves

#pragma unroll
    for (int i = 0; i < 4; ++i)
#pragma unroll
      for (int j = 0; j < 4; ++j) acc[i][j] = {0.f, 0.f, 0.f, 0.f};

#pragma unroll 2
    for (int kt = 0; kt < 8; ++kt) {
#pragma unroll
      for (int ks = 0; ks < 2; ++ks) {
        half8 bf[4];
#pragma unroll
        for (int j = 0; j < 4; ++j)
          bf[j] = *(const half8*)(xlds + (j * 16 + l16) * NCOL + kt * 64 +
                                  ((ks * 4 + quad) ^ l7) * 8);
        const size_t wk = (size_t)(kt * 64 + ks * 32 + quad * 8);
        half8 af[4];
#pragma unroll
        for (int i = 0; i < 4; ++i)
          af[i] = *(const half8*)(Wb + (size_t)(fb + i * 16 + l16) * NCOL + wk);
#pragma unroll
        for (int i = 0; i < 4; ++i)
#pragma unroll
          for (int j = 0; j < 4; ++j)
            acc[i][j] = __builtin_amdgcn_mfma_f32_16x16x32_f16(
                af[i], bf[j], acc[i][j], 0, 0, 0);
      }
    }

    const float g = gammas[t], eta = etas[t];
    __syncthreads();                  // all reads of x done before overwrite

    if (t < 10) {
#pragma unroll
      for (int i = 0; i < 4; ++i) {
        const int cw = ((fc + i * 2 + (quad >> 1)) ^ l7) * 8 + (quad & 1) * 4;
#pragma unroll
        for (int j = 0; j < 4; ++j) {
          half4v a4 = ayv[i][j];
          half4v xo = *(const half4v*)(xlds + (j * 16 + l16) * NCOL + cw);
          f32x4 u = acc[i][j];
          half4v xn;
#pragma unroll
          for (int r = 0; r < 4; ++r) {
            float val = fmaf(g, (float)a4[r] - u[r], (float)xo[r]);
            xn[r] = (_Float16)shrinkf(val, eta);
          }
          *(half4v*)(xlds + (j * 16 + l16) * NCOL + cw) = xn;
        }
      }
    } else {
#pragma unroll
      for (int i = 0; i < 4; ++i) {
        const int cw = ((fc + i * 2 + (quad >> 1)) ^ l7) * 8 + (quad & 1) * 4;
#pragma unroll
        for (int j = 0; j < 4; ++j) {
          half4v a4 = ayv[i][j];
          half4v xo = *(const half4v*)(xlds + (j * 16 + l16) * NCOL + cw);
          f32x4 u = acc[i][j];
          f32x4 o;
#pragma unroll
          for (int r = 0; r < 4; ++r) {
            float val = fmaf(g, (float)a4[r] - u[r], (float)xo[r]);
            o[r] = shrinkf(val, eta);
          }
          *(f32x4*)(out + (size_t)(b0 + j * 16 + l16) * NCOL + fb + i * 16 + quad * 4) = o;
        }
      }
    }
  }
}

extern "C" void kernel_launch(void* const* d_in, const int* in_sizes, int n_in,
                              void* d_out, int out_size, void* d_ws, size_t ws_size,
                              hipStream_t stream) {
  const float* y      = (const float*)d_in[0];
  const float* A      = (const float*)d_in[1];
  const float* B      = (const float*)d_in[2];
  const float* etas   = (const float*)d_in[3];
  const float* gammas = (const float*)d_in[4];

  char* ws = (char*)d_ws;
  _Float16* Wa = (_Float16*)ws;                       // 512*256*2 = 256 KB
  _Float16* Wb = (_Float16*)(ws + 262144);            // 512*512*2 = 512 KB

  hipLaunchKernelGGL(build_wa, dim3(512), dim3(256), 0, stream, A, Wa);
  hipLaunchKernelGGL(build_wb, dim3(1024), dim3(256), 0, stream, B, Wb);
  hipLaunchKernelGGL(lista_fused, dim3(1024), dim3(512), 0, stream,
                     y, Wa, Wb, (float*)d_out, gammas, etas);
}